// Round 7
// baseline (309.650 us; speedup 1.0000x reference)
//
#include <hip/hip_runtime.h>
#include <hip/hip_bf16.h>

typedef unsigned short u16;
typedef unsigned int   u32;
typedef __attribute__((ext_vector_type(8))) short  s16x8;
typedef __attribute__((ext_vector_type(4))) float  f32x4;
typedef __attribute__((ext_vector_type(4))) unsigned short u16x4;

#define MT    8192   // B*S tokens
#define DE    2048   // embed dim
#define NEXP  64     // experts
#define ERDIM 4096   // experts * rank

// round-to-nearest-even f32 -> bf16
__device__ __forceinline__ u16 to_bf16(float f) {
  u32 u = __builtin_bit_cast(u32, f);
  u32 r = u + 0x7fffu + ((u >> 16) & 1u);
  return (u16)(r >> 16);
}

__global__ void cvt_f32_bf16(const float* __restrict__ in, u16* __restrict__ out, int n) {
  const int stride = gridDim.x * blockDim.x;
  for (int i = blockIdx.x * blockDim.x + threadIdx.x; i * 4 < n; i += stride) {
    const float4 v = *reinterpret_cast<const float4*>(in + (size_t)i * 4);
    u16x4 o;
    o.x = to_bf16(v.x); o.y = to_bf16(v.y); o.z = to_bf16(v.z); o.w = to_bf16(v.w);
    *reinterpret_cast<u16x4*>(out + (size_t)i * 4) = o;
  }
}

// pack W[N][K] f32 row-major -> Bp[K/8][N][8] bf16 (k-granule-major).
// consecutive threads -> consecutive col -> coalesced 16B writes; reads are
// 32B chunks at stride K*4B, line-reused across the kg sweep (L2-resident).
__global__ void cvt_pack_bf16(const float* __restrict__ in, u16* __restrict__ out,
                              const int ncols, const int K) {
  const int nk8 = K >> 3;
  const int total = ncols * nk8;
  const int stride = gridDim.x * blockDim.x;
  for (int i = blockIdx.x * blockDim.x + threadIdx.x; i < total; i += stride) {
    const int col = i % ncols;
    const int kg  = i / ncols;
    const float* src = in + (size_t)col * K + kg * 8;
    const float4 v0 = *reinterpret_cast<const float4*>(src);
    const float4 v1 = *reinterpret_cast<const float4*>(src + 4);
    u16x4 o0, o1;
    o0.x = to_bf16(v0.x); o0.y = to_bf16(v0.y); o0.z = to_bf16(v0.z); o0.w = to_bf16(v0.w);
    o1.x = to_bf16(v1.x); o1.y = to_bf16(v1.y); o1.z = to_bf16(v1.z); o1.w = to_bf16(v1.w);
    u16* dst = out + ((size_t)kg * ncols + col) * 8;
    *reinterpret_cast<u16x4*>(dst)     = o0;
    *reinterpret_cast<u16x4*>(dst + 4) = o1;
  }
}

#define GLDS(gp, lp) __builtin_amdgcn_global_load_lds(                        \
    (const __attribute__((address_space(1))) void*)(gp),                      \
    (__attribute__((address_space(3))) void*)(lp), 16, 0, 0)

#define BAR() do { asm volatile("" ::: "memory");                             \
                   __builtin_amdgcn_s_barrier();                              \
                   asm volatile("" ::: "memory"); } while (0)

// C = A[M,K] * B[N,K]^T. A: bf16 row-major, staged via 4-slot A-only LDS ring
// (32 KiB), proven conflict-free granule-swizzled ds_read_b128. B: packed
// Bp[K/8][N][8] read DIRECTLY from global (L2-hot), double-buffered in regs,
// B(t+1) loads issued under the MFMA clusters (VMEM overlaps LDS+MFMA).
// In-queue order per body: [B(t+1) after A-reads, before GLDS A(t+3)] so the
// compiler's dep-wait for B(t) (vmcnt<=8) transitively retires A(t+1) before
// the tile barrier while keeping A-prefetch (t+2,t+3) in flight.
// FUSE=1: C_bf16[m,n] = bf16( silu(acc) * mask[m, n>>6] );  FUSE=0: C_f32 = acc
template<int FUSE, int K>
__global__ __launch_bounds__(512, 2) void gemm_bt(
    const u16* __restrict__ A, const u16* __restrict__ Bp,
    const float* __restrict__ mask, void* __restrict__ Cout,
    const int M, const int N)
{
  constexpr int BM = 256, BN = 256, BK = 32;
  constexpr int NT = K / BK;
  __shared__ __align__(16) u16 lds[32768];   // 4 slots x (A 8K elems = 16 KiB)

  const int nbn = N / BN;
  const int nwg = (int)gridDim.x;
  const int cpx = nwg >> 3;                      // nwg % 8 == 0 for all our grids
  const int bid = (int)blockIdx.x;
  const int swz = (bid & 7) * cpx + (bid >> 3);  // bijective XCD swizzle
  const int bm = (swz / nbn) * BM;
  const int bn = (swz % nbn) * BN;

  const int tid  = (int)threadIdx.x;
  const int lane = tid & 63;
  const int w    = tid >> 6;       // wave 0..7
  const int wr   = w >> 2;         // 0..1: M row-group (128 rows)
  const int wc   = w & 3;          // 0..3: N col-group (64 cols)

  const int fr = lane & 15;                          // fragment row/col
  const int hi = lane >> 4;                          // k-granule of this lane
  const int cp = hi ^ ((lane >> 1) & 3);             // swizzled LDS granule (read)

  // A staging: 512 threads x 16B cover 8 KiB (rows 0..127); second round +128.
  const int r0 = w * 16 + (lane >> 2);               // row, round 0
  const int cl = (lane & 3) ^ ((lane >> 3) & 3);     // inverse-swizzled src granule
  const u16* aS0 = A + (size_t)(bm + r0) * K + cl * 8;
  const u16* aS1 = A + (size_t)(bm + r0 + 128) * K + cl * 8;
  const int d0 = w * 512;          // LDS elem offset, round 0 (wave-uniform base)
  const int d1 = d0 + 4096;        // round 1 (+8 KiB)

  // packed-B per-lane base (elem offset): col = bn + wc*64 + fr, granule hi
  const u32 vb = ((u32)hi * (u32)N + (u32)(bn + wc * 64 + fr)) * 8u;
  const u32 tstep = 32u * (u32)N;                    // elems per K-tile in Bp

  f32x4 acc[8][4] = {};

  // ---- prologue: stage A tiles 0,1,2; load B(0) ----
#pragma unroll
  for (int t = 0; t < 3; ++t) {
    GLDS(aS0 + t * BK, lds + t * 8192 + d0);
    GLDS(aS1 + t * BK, lds + t * 8192 + d1);
  }
  s16x8 b0[4], b1[4];
#pragma unroll
  for (int n = 0; n < 4; ++n)
    b0[n] = *reinterpret_cast<const s16x8*>(Bp + vb + n * 128);
  asm volatile("s_waitcnt vmcnt(8)" ::: "memory");   // A slot0 landed
  BAR();

  // ---- main loop: 2 tiles per iteration, B reg double-buffer (no copies) ----
#pragma unroll 2
  for (int t = 0; t < NT; t += 2) {
    // ======== tile t: use b0, load b1 = B(t+1) ========
    {
      const u16* sA = lds + (t & 3) * 8192;
      s16x8 afr[8];
#pragma unroll
      for (int m = 0; m < 8; ++m)
        afr[m] = *reinterpret_cast<const s16x8*>(
            &sA[(wr * 128 + m * 16 + fr) * 32 + cp * 8]);
#pragma unroll
      for (int n = 0; n < 4; ++n)
        b1[n] = *reinterpret_cast<const s16x8*>(Bp + vb + (u32)(t + 1) * tstep + n * 128);
      if (t + 3 < NT) {
        u16* dst = lds + ((t + 3) & 3) * 8192;
        GLDS(aS0 + (size_t)(t + 3) * BK, dst + d0);
        GLDS(aS1 + (size_t)(t + 3) * BK, dst + d1);
      }
      __builtin_amdgcn_s_setprio(1);
#pragma unroll
      for (int m = 0; m < 8; ++m)
#pragma unroll
        for (int n = 0; n < 4; ++n)
          acc[m][n] = __builtin_amdgcn_mfma_f32_16x16x32_bf16(
              afr[m], b0[n], acc[m][n], 0, 0, 0);
      __builtin_amdgcn_s_setprio(0);
      BAR();
    }
    // ======== tile t+1: use b1, load b0 = B(t+2) ========
    {
      const int u = t + 1;
      const u16* sA = lds + (u & 3) * 8192;
      s16x8 afr[8];
#pragma unroll
      for (int m = 0; m < 8; ++m)
        afr[m] = *reinterpret_cast<const s16x8*>(
            &sA[(wr * 128 + m * 16 + fr) * 32 + cp * 8]);
      if (u + 1 < NT)
#pragma unroll
        for (int n = 0; n < 4; ++n)
          b0[n] = *reinterpret_cast<const s16x8*>(Bp + vb + (u32)(u + 1) * tstep + n * 128);
      if (u + 3 < NT) {
        u16* dst = lds + ((u + 3) & 3) * 8192;
        GLDS(aS0 + (size_t)(u + 3) * BK, dst + d0);
        GLDS(aS1 + (size_t)(u + 3) * BK, dst + d1);
      }
      __builtin_amdgcn_s_setprio(1);
#pragma unroll
      for (int m = 0; m < 8; ++m)
#pragma unroll
        for (int n = 0; n < 4; ++n)
          acc[m][n] = __builtin_amdgcn_mfma_f32_16x16x32_bf16(
              afr[m], b1[n], acc[m][n], 0, 0, 0);
      __builtin_amdgcn_s_setprio(0);
      if (u + 1 < NT) BAR();
    }
  }

  // ---- epilogue: C/D layout col=lane&15, row=(lane>>4)*4 + j ----
  const int rgrp = hi * 4;
  if (FUSE) {
    u16* H = (u16*)Cout;
    const int ew = (bn + wc * 64) >> 6;  // wave's 64-col span = exactly one expert
#pragma unroll
    for (int m = 0; m < 8; ++m) {
#pragma unroll
      for (int j = 0; j < 4; ++j) {
        const int grow = bm + wr * 128 + m * 16 + rgrp + j;
        const float mv = mask[(size_t)grow * NEXP + ew];
#pragma unroll
        for (int n = 0; n < 4; ++n) {
          const int gcol = bn + wc * 64 + n * 16 + fr;
          float v = acc[m][n][j];
          v = v / (1.0f + __expf(-v));   // silu
          H[(size_t)grow * N + gcol] = to_bf16(v * mv);
        }
      }
    }
  } else {
    float* O = (float*)Cout;
#pragma unroll
    for (int m = 0; m < 8; ++m) {
#pragma unroll
      for (int j = 0; j < 4; ++j) {
        const int grow = bm + wr * 128 + m * 16 + rgrp + j;
#pragma unroll
        for (int n = 0; n < 4; ++n) {
          const int gcol = bn + wc * 64 + n * 16 + fr;
          O[(size_t)grow * N + gcol] = acc[m][n][j];
        }
      }
    }
  }
}

extern "C" void kernel_launch(void* const* d_in, const int* in_sizes, int n_in,
                              void* d_out, int out_size, void* d_ws, size_t ws_size,
                              hipStream_t stream) {
  const float* x     = (const float*)d_in[0];
  const float* emask = (const float*)d_in[1];
  const float* w_up  = (const float*)d_in[2];
  const float* w_dn  = (const float*)d_in[3];
  float* out = (float*)d_out;

  // workspace (bf16): x[8192,2048] | Bp1[2048/8][4096][8] | Bp2[4096/8][2048][8] | H[8192,4096]
  const size_t need = ((size_t)MT * DE + (size_t)ERDIM * DE + (size_t)DE * ERDIM +
                       (size_t)MT * ERDIM) * sizeof(u16);
  if (ws_size < need) return;

  u16* xb  = (u16*)d_ws;
  u16* bp1 = xb  + (size_t)MT * DE;
  u16* bp2 = bp1 + (size_t)ERDIM * DE;
  u16* hb  = bp2 + (size_t)DE * ERDIM;

  hipLaunchKernelGGL(cvt_f32_bf16, dim3(2048), dim3(256), 0, stream, x, xb, MT * DE);
  // w_up [4096 cols][K=2048] -> Bp1;  w_dn [2048 cols][K=4096] -> Bp2
  hipLaunchKernelGGL(cvt_pack_bf16, dim3(2048), dim3(256), 0, stream, w_up, bp1, ERDIM, DE);
  hipLaunchKernelGGL(cvt_pack_bf16, dim3(2048), dim3(256), 0, stream, w_dn, bp2, DE, ERDIM);

  // GEMM1: H = silu(X @ Wup^T) * mask   [M=8192, N=4096, K=2048] -> 512 blocks
  hipLaunchKernelGGL((gemm_bt<1, DE>), dim3((MT / 256) * (ERDIM / 256)), dim3(512), 0, stream,
                     xb, bp1, emask, (void*)hb, MT, ERDIM);
  // GEMM2: out = H @ Wdown^T             [M=8192, N=2048, K=4096] -> 256 blocks
  hipLaunchKernelGGL((gemm_bt<0, ERDIM>), dim3((MT / 256) * (DE / 256)), dim3(512), 0, stream,
                     hb, bp2, nullptr, (void*)out, MT, DE);
}